// Round 7
// baseline (239.535 us; speedup 1.0000x reference)
//
#include <hip/hip_runtime.h>
#include <hip/hip_bf16.h>

// DeepFM on MI355X. B=16384, NF=50, K=16, V=1e6, H=400, d=800.
// index = repeat(arange(B), NF) -> sample s owns rows [s*50, s*50+50).
//
// Pipeline (3 launches):
//   k1 prep:    blocks 0..607 transpose W0->W0t [512][800], W1->W1t [512][416]
//               (bf16, n-major, zero-padded); block 0 also zeroes the gemm2
//               completion counters; blocks 608.. gather: per-sample
//               first+second order (fp32) -> fs; emb -> x bf16 [16384][800]
//   k2 gemm1:   h0 = relu(x @ W0 + b0)  bf16 [16384][416] (cols 400..415 = 0)
//   k3 gemm2:   partial[s][slot] = sum_cols relu(h0@W1+b1)*W2; the LAST of the
//               4 n-blocks per m-strip (device-scope counter) sums the 8 slots
//               and writes out = sigmoid(fs + relu(. + b2)) for its 128 rows.
//
// GEMM: 128x128 tile, 4 waves (2Mx2N), acc 4x4, BK=64 (two BK=32 planes per
// barrier pair; odd-KT tail does one plane) — measured-best config (R4/R6);
// BK=128 regressed (R5, matches learn_hip m132). global_load_lds width=16
// staging, LDS-repacked coalesced bf16 epilogue.

#define BATCH 16384
#define NFLD  50
#define EK    16
#define DDIM  800   // NF*K  (= gemm1 K, exact, 25 planes)
#define HDIM  400
#define HPAD  416   // HDIM padded to mult of 32 (= gemm2 K, 13 planes)
#define NPAD  512   // HDIM padded to mult of 128 (N tiles of 128)

#define TB_W0 400            // 25 k-tiles x 16 n-tiles for W0 transpose
#define TB_W1 208            // 13 k-tiles x 16 n-tiles for W1 transpose
#define TBLK  (TB_W0 + TB_W1)
#define GBLK  (BATCH / 8)    // gather blocks: 8 samples/block (2 per wave)

typedef __attribute__((ext_vector_type(8))) __bf16 bf16x8;
typedef __attribute__((ext_vector_type(4))) float  f32x4;

typedef const __attribute__((address_space(1))) unsigned int* gas_u32p;
typedef __attribute__((address_space(3))) unsigned int*       las_u32p;

__device__ __forceinline__ void gld_lds16(const void* g, void* l) {
    // async global->LDS, 16B/lane; HW dest = wave-uniform base + lane*16.
    __builtin_amdgcn_global_load_lds((gas_u32p)g, (las_u32p)l, 16, 0, 0);
}

// ---------------- k1: transpose (blocks < TBLK) + gather (rest) ----------------
__global__ __launch_bounds__(256) void prep_kernel(
    const float* __restrict__ W0, const float* __restrict__ W1,
    __hip_bfloat16* __restrict__ W0t, __hip_bfloat16* __restrict__ W1t,
    const int* __restrict__ feats, const float* __restrict__ values,
    const float* __restrict__ biasp, const float* __restrict__ weights,
    const float* __restrict__ embedding,
    float* __restrict__ fs, __hip_bfloat16* __restrict__ x,
    int* __restrict__ cnt)
{
    const int bid = blockIdx.x;
    if (bid < TBLK) {
        // block 0 also zeroes the gemm2 completion counters (runs pre-gemm2)
        if (bid == 0 && threadIdx.x < BATCH / 128) cnt[threadIdx.x] = 0;

        // ---- tiled transpose f32 -> bf16 with zero pad ----
        const int which = bid >= TB_W0;
        const int i  = which ? bid - TB_W0 : bid;
        const int nx = which ? 13 : 25;                  // k-tiles
        const int bx = i % nx, by = i / nx;
        const float* src = which ? W1 : W0;
        __hip_bfloat16* dst = which ? W1t : W0t;
        const int srcK = which ? HDIM : DDIM;            // source rows (k)
        const int dstCols = which ? HPAD : DDIM;

        __shared__ float tile[32][33];
        const int tx = threadIdx.x & 31, ty = threadIdx.x >> 5;   // 32 x 8
        const int k0 = bx * 32, n0 = by * 32;
#pragma unroll
        for (int r = 0; r < 4; ++r) {
            int k = k0 + ty + r * 8;
            int n = n0 + tx;
            float v = (k < srcK && n < HDIM) ? src[(long)k * HDIM + n] : 0.f;
            tile[ty + r * 8][tx] = v;
        }
        __syncthreads();
#pragma unroll
        for (int r = 0; r < 4; ++r) {
            int n = n0 + ty + r * 8;   // dst row
            int k = k0 + tx;           // dst col
            if (k < dstCols)
                dst[(long)n * dstCols + k] = __float2bfloat16(tile[tx][ty + r * 8]);
        }
        return;
    }

    // ---- gather + first/second order: 2 samples per wave ----
    const int wave = threadIdx.x >> 6;
    const int lane = threadIdx.x & 63;
    const int r    = lane >> 2, c = lane & 3;
    const int sbase = (bid - TBLK) * 8 + wave * 2;

    int   f[2] = {0, 0}; float v[2] = {0.f, 0.f}; float wsum[2] = {0.f, 0.f};
#pragma unroll
    for (int q = 0; q < 2; ++q) {
        const long base = (long)(sbase + q) * NFLD;
        if (lane < NFLD) {
            f[q] = feats[base + lane];
            v[q] = values[base + lane];
            wsum[q] = weights[f[q]] * v[q];
        }
    }

    // broadcast all indices, then fire all 8 gathers back-to-back (MLP)
    int   fj[2][4]; float vj[2][4];
#pragma unroll
    for (int q = 0; q < 2; ++q)
#pragma unroll
        for (int p = 0; p < 4; ++p) {
            const int j = p * 16 + r;
            if (p < 3 || r < 2) {
                fj[q][p] = __shfl(f[q], j);
                vj[q][p] = __shfl(v[q], j);
            }
        }
    float4 e[2][4];
#pragma unroll
    for (int q = 0; q < 2; ++q)
#pragma unroll
        for (int p = 0; p < 4; ++p)
            if (p < 3 || r < 2)
                e[q][p] = *(const float4*)(embedding + (long)fj[q][p] * EK + c * 4);

#pragma unroll
    for (int q = 0; q < 2; ++q) {
        const int s = sbase + q;
        f32x4 s1 = {0.f, 0.f, 0.f, 0.f}, s2 = {0.f, 0.f, 0.f, 0.f};
#pragma unroll
        for (int p = 0; p < 4; ++p) {
            const int j = p * 16 + r;
            if (p < 3 || r < 2) {                 // j < 50
                f32x4 ef = {e[q][p].x, e[q][p].y, e[q][p].z, e[q][p].w};
                f32x4 ev = ef * vj[q][p];
                s1 += ev;
                s2 += ev * ev;
                __hip_bfloat16 pk[4] = {
                    __float2bfloat16(e[q][p].x), __float2bfloat16(e[q][p].y),
                    __float2bfloat16(e[q][p].z), __float2bfloat16(e[q][p].w)};
                *(uint2*)&x[(long)s * DDIM + j * EK + c * 4] = *(uint2*)pk;
            }
        }
#pragma unroll
        for (int m = 4; m <= 32; m <<= 1) {
            s1.x += __shfl_xor(s1.x, m); s1.y += __shfl_xor(s1.y, m);
            s1.z += __shfl_xor(s1.z, m); s1.w += __shfl_xor(s1.w, m);
            s2.x += __shfl_xor(s2.x, m); s2.y += __shfl_xor(s2.y, m);
            s2.z += __shfl_xor(s2.z, m); s2.w += __shfl_xor(s2.w, m);
        }
        float t = (s1.x * s1.x - s2.x) + (s1.y * s1.y - s2.y)
                + (s1.z * s1.z - s2.z) + (s1.w * s1.w - s2.w);
        t += __shfl_xor(t, 1); t += __shfl_xor(t, 2);
        float w = wsum[q];
        w += __shfl_xor(w, 1);  w += __shfl_xor(w, 2);
        w += __shfl_xor(w, 4);  w += __shfl_xor(w, 8);
        w += __shfl_xor(w, 16); w += __shfl_xor(w, 32);
        if (lane == 0) fs[s] = w + 0.5f * t + biasp[0];
    }
}

// ---------------- k2/k3: GEMM + bias + relu ----------------
// MODE 0: C = bf16 h0 [M][LDC]; global cols >= HDIM written as 0 (up to LDC).
// MODE 1: C = f32 partial [M][8]; per-row dot with W2 over this block's cols,
//         slot = blockIdx.x*2 + waveN. Last n-block per m-strip (device-scope
//         counter) sums slots + writes sigmoid output.
// grid = (4 n-tiles, 128 m-tiles), block = 256 (2M x 2N waves), tile 128x128.
// K-loop: BK=64 = two BK=32 planes per barrier pair; odd KT -> 1-plane tail.
#define OSTRIDE 136   // epilogue LDS row stride (bf16): 272B, 16B-aligned
template <int KDIM, int MODE, int LDC>
__global__ __launch_bounds__(256) void gemm_relu_kernel(
    const __hip_bfloat16* __restrict__ A,
    const __hip_bfloat16* __restrict__ Bt,
    const float* __restrict__ biasp,
    const float* __restrict__ W2,
    void* __restrict__ C,
    const float* __restrict__ b2p,
    const float* __restrict__ fs,
    float* __restrict__ out,
    int* __restrict__ cnt)
{
    constexpr int KT = KDIM / 32;
    // union: staging (2 planes x (A 8KB + B 8KB) = 32KB) / epilogue out (34KB)
    __shared__ __align__(16) char lds[128 * OSTRIDE * 2];
    __shared__ int sDone;
    __hip_bfloat16* sA = (__hip_bfloat16*)lds;          // [2][128*32]
    __hip_bfloat16* sB = sA + 2 * 4096;                 // [2][128*32]
    __hip_bfloat16* sO = (__hip_bfloat16*)lds;          // [128][OSTRIDE]

    const int tid  = threadIdx.x;
    const int wave = tid >> 6, lane = tid & 63;
    const int l16  = lane & 15, quad = lane >> 4;
    const int waveM = wave & 1, waveN = wave >> 1;
    const int m0 = blockIdx.y * 128;
    const int n0 = blockIdx.x * 128;

    f32x4 acc[4][4] = {};

    // staging: chunk = 16 rows x 32 cols (1KB); lane i -> row i>>2, col (i&3)*8.
    const long ar0 = (long)(m0 + wave * 16 + (lane >> 2)) * KDIM;
    const long ar1 = ar0 + (long)64 * KDIM;
    const long br0 = (long)(n0 + wave * 16 + (lane >> 2)) * KDIM;
    const long br1 = br0 + (long)64 * KDIM;
    const int  ac  = (lane & 3) * 8;
    __hip_bfloat16* ldsA0 = sA + wave * 512 + lane * 8;
    __hip_bfloat16* ldsA1 = sA + 2048 + wave * 512 + lane * 8;
    __hip_bfloat16* ldsB0 = sB + wave * 512 + lane * 8;
    __hip_bfloat16* ldsB1 = sB + 2048 + wave * 512 + lane * 8;

    auto stage = [&](int plane, int h) {
        const int k0 = plane * 32;
        gld_lds16(A  + ar0 + k0 + ac, ldsA0 + h * 4096);
        gld_lds16(A  + ar1 + k0 + ac, ldsA1 + h * 4096);
        gld_lds16(Bt + br0 + k0 + ac, ldsB0 + h * 4096);
        gld_lds16(Bt + br1 + k0 + ac, ldsB1 + h * 4096);
    };
    auto compute = [&](int h) {
        bf16x8 af[4], bfr[4];
#pragma unroll
        for (int i = 0; i < 4; ++i)
            af[i] = *(const bf16x8*)&sA[h * 4096 + (waveM * 64 + i * 16 + l16) * 32 + quad * 8];
#pragma unroll
        for (int j = 0; j < 4; ++j)
            bfr[j] = *(const bf16x8*)&sB[h * 4096 + (waveN * 64 + j * 16 + l16) * 32 + quad * 8];
#pragma unroll
        for (int i = 0; i < 4; ++i)
#pragma unroll
            for (int j = 0; j < 4; ++j)
                acc[i][j] = __builtin_amdgcn_mfma_f32_16x16x32_bf16(
                    af[i], bfr[j], acc[i][j], 0, 0, 0);
    };

    for (int kt = 0; kt + 1 < KT; kt += 2) {
        stage(kt, 0); stage(kt + 1, 1);
        __syncthreads();   // compiler drains vmcnt before s_barrier
        compute(0); compute(1);
        __syncthreads();
    }
    if constexpr (KT & 1) {
        stage(KT - 1, 0);
        __syncthreads();
        compute(0);
        __syncthreads();
    }

    const float bias = biasp[0];
    if constexpr (MODE == 0) {
        // repack through LDS -> coalesced dwordx4 stores
#pragma unroll
        for (int i = 0; i < 4; ++i) {
            const int rl = waveM * 64 + i * 16 + quad * 4;    // C/D: row=quad*4+r
#pragma unroll
            for (int j = 0; j < 4; ++j) {
                const int cl = waveN * 64 + j * 16 + l16;     // C/D: col=l16
                const int gcol = n0 + cl;
#pragma unroll
                for (int r = 0; r < 4; ++r) {
                    float v = acc[i][j][r] + bias;
                    v = v > 0.f ? v : 0.f;
                    if (gcol >= HDIM) v = 0.f;                // pad cols -> 0
                    sO[(rl + r) * OSTRIDE + cl] = __float2bfloat16(v);
                }
            }
        }
        __syncthreads();
        __hip_bfloat16* Cp = (__hip_bfloat16*)C;
#pragma unroll
        for (int q = 0; q < 8; ++q) {
            const int flat = tid + q * 256;        // 0..2047
            const int rl = flat >> 4, c16 = flat & 15;
            const int gcol = n0 + c16 * 8;
            if (gcol < LDC)
                *(float4*)&Cp[(long)(m0 + rl) * LDC + gcol] =
                    *(const float4*)&sO[rl * OSTRIDE + c16 * 8];
        }
    } else {
        // fused h1 . W2 partial dot; W2=0 past HDIM kills padded-col relu(b1)
        float* part = (float*)C;
        float w2v[4];
#pragma unroll
        for (int j = 0; j < 4; ++j) {
            int col = n0 + waveN * 64 + j * 16 + l16;
            w2v[j] = (col < HDIM) ? W2[col] : 0.f;
        }
        const int slot = blockIdx.x * 2 + waveN;
#pragma unroll
        for (int i = 0; i < 4; ++i) {
#pragma unroll
            for (int r = 0; r < 4; ++r) {
                float p = 0.f;
#pragma unroll
                for (int j = 0; j < 4; ++j) {
                    float v = acc[i][j][r] + bias;
                    v = v > 0.f ? v : 0.f;
                    p += v * w2v[j];
                }
                p += __shfl_xor(p, 1); p += __shfl_xor(p, 2);
                p += __shfl_xor(p, 4); p += __shfl_xor(p, 8);
                if (l16 == 0) {
                    int row = m0 + waveM * 64 + i * 16 + quad * 4 + r;
                    part[(long)row * 8 + slot] = p;
                }
            }
        }
        // last-block-done: release partials, bump m-strip counter
        __threadfence();                       // device-scope release (wb L2)
        __syncthreads();
        if (tid == 0) {
            int old = atomicAdd(&cnt[blockIdx.y], 1);   // device scope
            sDone = (old == 3);
        }
        __syncthreads();
        if (sDone) {
            __threadfence();                   // acquire (inv stale lines)
            if (tid < 128) {
                const int s = m0 + tid;
                float sum = 0.f;
#pragma unroll
                for (int q = 0; q < 8; ++q)
                    sum += __hip_atomic_load(&part[(long)s * 8 + q],
                                             __ATOMIC_RELAXED,
                                             __HIP_MEMORY_SCOPE_AGENT);
                float h = sum + b2p[0];
                h = h > 0.f ? h : 0.f;
                float z = fs[s] + h;
                out[s] = 1.f / (1.f + __expf(-z));
            }
        }
    }
}

extern "C" void kernel_launch(void* const* d_in, const int* in_sizes, int n_in,
                              void* d_out, int out_size, void* d_ws, size_t ws_size,
                              hipStream_t stream)
{
    // 0 index, 1 feats, 2 values, 3 bias, 4 weights, 5 embedding,
    // 6 W0, 7 b0, 8 W1, 9 b1, 10 W2, 11 b2, 12 batch_size
    const int*   feats     = (const int*)d_in[1];
    const float* values    = (const float*)d_in[2];
    const float* bias      = (const float*)d_in[3];
    const float* weights   = (const float*)d_in[4];
    const float* embedding = (const float*)d_in[5];
    const float* W0 = (const float*)d_in[6];
    const float* b0 = (const float*)d_in[7];
    const float* W1 = (const float*)d_in[8];
    const float* b1 = (const float*)d_in[9];
    const float* W2 = (const float*)d_in[10];
    const float* b2 = (const float*)d_in[11];

    char* ws = (char*)d_ws;
    size_t off = 0;
    auto alloc = [&](size_t bytes) {
        void* p = ws + off;
        off += (bytes + 255) & ~(size_t)255;
        return p;
    };
    float*          fs   = (float*)alloc((size_t)BATCH * 4);
    __hip_bfloat16* x    = (__hip_bfloat16*)alloc((size_t)BATCH * DDIM * 2);
    __hip_bfloat16* h0   = (__hip_bfloat16*)alloc((size_t)BATCH * HPAD * 2);
    float*          part = (float*)alloc((size_t)BATCH * 8 * 4);
    __hip_bfloat16* W0t  = (__hip_bfloat16*)alloc((size_t)NPAD * DDIM * 2);
    __hip_bfloat16* W1t  = (__hip_bfloat16*)alloc((size_t)NPAD * HPAD * 2);
    int*            cnt  = (int*)alloc((size_t)(BATCH / 128) * 4);
    (void)ws_size; (void)in_sizes; (void)n_in; (void)out_size;

    prep_kernel<<<dim3(TBLK + GBLK), 256, 0, stream>>>(
        W0, W1, W0t, W1t, feats, values, bias, weights, embedding, fs, x, cnt);
    gemm_relu_kernel<DDIM, 0, HPAD>
        <<<dim3(NPAD / 128, BATCH / 128), 256, 0, stream>>>(
        x, W0t, b0, nullptr, (void*)h0, nullptr, nullptr, nullptr, nullptr);
    gemm_relu_kernel<HPAD, 1, 8>
        <<<dim3(NPAD / 128, BATCH / 128), 256, 0, stream>>>(
        h0, W1t, b1, W2, (void*)part, b2, fs, (float*)d_out, cnt);
}

// Round 8
// 178.808 us; speedup vs baseline: 1.3396x; 1.3396x over previous
//
#include <hip/hip_runtime.h>
#include <hip/hip_bf16.h>

// DeepFM on MI355X. B=16384, NF=50, K=16, V=1e6, H=400, d=800.
// index = repeat(arange(B), NF) -> sample s owns rows [s*50, s*50+50).
//
// Pipeline (4 launches):
//   k1 prep:    blocks 0..607 transpose W0->W0t [512][800], W1->W1t [512][416]
//               (bf16, n-major, zero-padded); blocks 608.. gather: per-sample
//               first+second order (fp32) -> fs; emb -> x bf16 [16384][800]
//               (4 samples/wave: 16 embedding-line loads in flight)
//   k2 gemm1:   h0 = relu(x @ W0 + b0)  bf16 [16384][416] (cols 400..415 = 0)
//   k3 gemm2:   partial[s][slot] = sum_cols relu(h0@W1+b1)*W2  (h1 stays on-chip)
//   k4 final:   out = sigmoid(fs + relu(sum partial + b2))
//
// GEMM: 128x128 tile, 4 waves (2Mx2N), acc 4x4, BK=64 (two BK=32 planes per
// barrier pair; odd-KT tail does one plane) — measured-best config (R4/R6);
// BK=128 regressed (R5 = m132), per-block device-scope fence fusion regressed
// hard (R7: +60us, L2-flush serialization). global_load_lds width=16 staging,
// LDS-repacked coalesced bf16 epilogue.

#define BATCH 16384
#define NFLD  50
#define EK    16
#define DDIM  800   // NF*K  (= gemm1 K, exact, 25 planes)
#define HDIM  400
#define HPAD  416   // HDIM padded to mult of 32 (= gemm2 K, 13 planes)
#define NPAD  512   // HDIM padded to mult of 128 (N tiles of 128)

#define TB_W0 400            // 25 k-tiles x 16 n-tiles for W0 transpose
#define TB_W1 208            // 13 k-tiles x 16 n-tiles for W1 transpose
#define TBLK  (TB_W0 + TB_W1)
#define GBLK  (BATCH / 16)   // gather blocks: 16 samples/block (4 per wave)

typedef __attribute__((ext_vector_type(8))) __bf16 bf16x8;
typedef __attribute__((ext_vector_type(4))) float  f32x4;

typedef const __attribute__((address_space(1))) unsigned int* gas_u32p;
typedef __attribute__((address_space(3))) unsigned int*       las_u32p;

__device__ __forceinline__ void gld_lds16(const void* g, void* l) {
    // async global->LDS, 16B/lane; HW dest = wave-uniform base + lane*16.
    __builtin_amdgcn_global_load_lds((gas_u32p)g, (las_u32p)l, 16, 0, 0);
}

// ---------------- k1: transpose (blocks < TBLK) + gather (rest) ----------------
__global__ __launch_bounds__(256) void prep_kernel(
    const float* __restrict__ W0, const float* __restrict__ W1,
    __hip_bfloat16* __restrict__ W0t, __hip_bfloat16* __restrict__ W1t,
    const int* __restrict__ feats, const float* __restrict__ values,
    const float* __restrict__ biasp, const float* __restrict__ weights,
    const float* __restrict__ embedding,
    float* __restrict__ fs, __hip_bfloat16* __restrict__ x)
{
    const int bid = blockIdx.x;
    if (bid < TBLK) {
        // ---- tiled transpose f32 -> bf16 with zero pad ----
        const int which = bid >= TB_W0;
        const int i  = which ? bid - TB_W0 : bid;
        const int nx = which ? 13 : 25;                  // k-tiles
        const int bx = i % nx, by = i / nx;
        const float* src = which ? W1 : W0;
        __hip_bfloat16* dst = which ? W1t : W0t;
        const int srcK = which ? HDIM : DDIM;            // source rows (k)
        const int dstCols = which ? HPAD : DDIM;

        __shared__ float tile[32][33];
        const int tx = threadIdx.x & 31, ty = threadIdx.x >> 5;   // 32 x 8
        const int k0 = bx * 32, n0 = by * 32;
#pragma unroll
        for (int r = 0; r < 4; ++r) {
            int k = k0 + ty + r * 8;
            int n = n0 + tx;
            float v = (k < srcK && n < HDIM) ? src[(long)k * HDIM + n] : 0.f;
            tile[ty + r * 8][tx] = v;
        }
        __syncthreads();
#pragma unroll
        for (int r = 0; r < 4; ++r) {
            int n = n0 + ty + r * 8;   // dst row
            int k = k0 + tx;           // dst col
            if (k < dstCols)
                dst[(long)n * dstCols + k] = __float2bfloat16(tile[tx][ty + r * 8]);
        }
        return;
    }

    // ---- gather + first/second order: 4 samples per wave ----
    const int wave = threadIdx.x >> 6;
    const int lane = threadIdx.x & 63;
    const int r    = lane >> 2, c = lane & 3;
    const int sbase = (bid - TBLK) * 16 + wave * 4;

    int   f[4] = {0, 0, 0, 0};
    float v[4] = {0.f, 0.f, 0.f, 0.f};
    float wsum[4] = {0.f, 0.f, 0.f, 0.f};
#pragma unroll
    for (int q = 0; q < 4; ++q) {
        const long base = (long)(sbase + q) * NFLD;
        if (lane < NFLD) {
            f[q] = feats[base + lane];
            v[q] = values[base + lane];
            wsum[q] = weights[f[q]] * v[q];
        }
    }

    // broadcast all indices, then fire all 16 gathers back-to-back (MLP)
    int   fj[4][4]; float vj[4][4];
#pragma unroll
    for (int q = 0; q < 4; ++q)
#pragma unroll
        for (int p = 0; p < 4; ++p) {
            const int j = p * 16 + r;
            if (p < 3 || r < 2) {
                fj[q][p] = __shfl(f[q], j);
                vj[q][p] = __shfl(v[q], j);
            }
        }
    float4 e[4][4];
#pragma unroll
    for (int q = 0; q < 4; ++q)
#pragma unroll
        for (int p = 0; p < 4; ++p)
            if (p < 3 || r < 2)
                e[q][p] = *(const float4*)(embedding + (long)fj[q][p] * EK + c * 4);

#pragma unroll
    for (int q = 0; q < 4; ++q) {
        const int s = sbase + q;
        f32x4 s1 = {0.f, 0.f, 0.f, 0.f}, s2 = {0.f, 0.f, 0.f, 0.f};
#pragma unroll
        for (int p = 0; p < 4; ++p) {
            const int j = p * 16 + r;
            if (p < 3 || r < 2) {                 // j < 50
                f32x4 ef = {e[q][p].x, e[q][p].y, e[q][p].z, e[q][p].w};
                f32x4 ev = ef * vj[q][p];
                s1 += ev;
                s2 += ev * ev;
                __hip_bfloat16 pk[4] = {
                    __float2bfloat16(e[q][p].x), __float2bfloat16(e[q][p].y),
                    __float2bfloat16(e[q][p].z), __float2bfloat16(e[q][p].w)};
                *(uint2*)&x[(long)s * DDIM + j * EK + c * 4] = *(uint2*)pk;
            }
        }
#pragma unroll
        for (int m = 4; m <= 32; m <<= 1) {
            s1.x += __shfl_xor(s1.x, m); s1.y += __shfl_xor(s1.y, m);
            s1.z += __shfl_xor(s1.z, m); s1.w += __shfl_xor(s1.w, m);
            s2.x += __shfl_xor(s2.x, m); s2.y += __shfl_xor(s2.y, m);
            s2.z += __shfl_xor(s2.z, m); s2.w += __shfl_xor(s2.w, m);
        }
        float t = (s1.x * s1.x - s2.x) + (s1.y * s1.y - s2.y)
                + (s1.z * s1.z - s2.z) + (s1.w * s1.w - s2.w);
        t += __shfl_xor(t, 1); t += __shfl_xor(t, 2);
        float w = wsum[q];
        w += __shfl_xor(w, 1);  w += __shfl_xor(w, 2);
        w += __shfl_xor(w, 4);  w += __shfl_xor(w, 8);
        w += __shfl_xor(w, 16); w += __shfl_xor(w, 32);
        if (lane == 0) fs[s] = w + 0.5f * t + biasp[0];
    }
}

// ---------------- k2/k3: GEMM + bias + relu ----------------
// MODE 0: C = bf16 h0 [M][LDC]; global cols >= HDIM written as 0 (up to LDC).
// MODE 1: C = f32 partial [M][8]; per-row dot with W2 over this block's cols,
//         slot = blockIdx.x*2 + waveN.
// grid = (4 n-tiles, 128 m-tiles), block = 256 (2M x 2N waves), tile 128x128.
// K-loop: BK=64 = two BK=32 planes per barrier pair; odd KT -> 1-plane tail.
#define OSTRIDE 136   // epilogue LDS row stride (bf16): 272B, 16B-aligned
template <int KDIM, int MODE, int LDC>
__global__ __launch_bounds__(256) void gemm_relu_kernel(
    const __hip_bfloat16* __restrict__ A,
    const __hip_bfloat16* __restrict__ Bt,
    const float* __restrict__ biasp,
    const float* __restrict__ W2,
    void* __restrict__ C)
{
    constexpr int KT = KDIM / 32;
    // union: staging (2 planes x (A 8KB + B 8KB) = 32KB) / epilogue out (34KB)
    __shared__ __align__(16) char lds[128 * OSTRIDE * 2];
    __hip_bfloat16* sA = (__hip_bfloat16*)lds;          // [2][128*32]
    __hip_bfloat16* sB = sA + 2 * 4096;                 // [2][128*32]
    __hip_bfloat16* sO = (__hip_bfloat16*)lds;          // [128][OSTRIDE]

    const int tid  = threadIdx.x;
    const int wave = tid >> 6, lane = tid & 63;
    const int l16  = lane & 15, quad = lane >> 4;
    const int waveM = wave & 1, waveN = wave >> 1;
    const int m0 = blockIdx.y * 128;
    const int n0 = blockIdx.x * 128;

    f32x4 acc[4][4] = {};

    // staging: chunk = 16 rows x 32 cols (1KB); lane i -> row i>>2, col (i&3)*8.
    const long ar0 = (long)(m0 + wave * 16 + (lane >> 2)) * KDIM;
    const long ar1 = ar0 + (long)64 * KDIM;
    const long br0 = (long)(n0 + wave * 16 + (lane >> 2)) * KDIM;
    const long br1 = br0 + (long)64 * KDIM;
    const int  ac  = (lane & 3) * 8;
    __hip_bfloat16* ldsA0 = sA + wave * 512 + lane * 8;
    __hip_bfloat16* ldsA1 = sA + 2048 + wave * 512 + lane * 8;
    __hip_bfloat16* ldsB0 = sB + wave * 512 + lane * 8;
    __hip_bfloat16* ldsB1 = sB + 2048 + wave * 512 + lane * 8;

    auto stage = [&](int plane, int h) {
        const int k0 = plane * 32;
        gld_lds16(A  + ar0 + k0 + ac, ldsA0 + h * 4096);
        gld_lds16(A  + ar1 + k0 + ac, ldsA1 + h * 4096);
        gld_lds16(Bt + br0 + k0 + ac, ldsB0 + h * 4096);
        gld_lds16(Bt + br1 + k0 + ac, ldsB1 + h * 4096);
    };
    auto compute = [&](int h) {
        bf16x8 af[4], bfr[4];
#pragma unroll
        for (int i = 0; i < 4; ++i)
            af[i] = *(const bf16x8*)&sA[h * 4096 + (waveM * 64 + i * 16 + l16) * 32 + quad * 8];
#pragma unroll
        for (int j = 0; j < 4; ++j)
            bfr[j] = *(const bf16x8*)&sB[h * 4096 + (waveN * 64 + j * 16 + l16) * 32 + quad * 8];
#pragma unroll
        for (int i = 0; i < 4; ++i)
#pragma unroll
            for (int j = 0; j < 4; ++j)
                acc[i][j] = __builtin_amdgcn_mfma_f32_16x16x32_bf16(
                    af[i], bfr[j], acc[i][j], 0, 0, 0);
    };

    for (int kt = 0; kt + 1 < KT; kt += 2) {
        stage(kt, 0); stage(kt + 1, 1);
        __syncthreads();   // compiler drains vmcnt before s_barrier
        compute(0); compute(1);
        __syncthreads();
    }
    if constexpr (KT & 1) {
        stage(KT - 1, 0);
        __syncthreads();
        compute(0);
        __syncthreads();
    }

    const float bias = biasp[0];
    if constexpr (MODE == 0) {
        // repack through LDS -> coalesced dwordx4 stores
#pragma unroll
        for (int i = 0; i < 4; ++i) {
            const int rl = waveM * 64 + i * 16 + quad * 4;    // C/D: row=quad*4+r
#pragma unroll
            for (int j = 0; j < 4; ++j) {
                const int cl = waveN * 64 + j * 16 + l16;     // C/D: col=l16
                const int gcol = n0 + cl;
#pragma unroll
                for (int r = 0; r < 4; ++r) {
                    float v = acc[i][j][r] + bias;
                    v = v > 0.f ? v : 0.f;
                    if (gcol >= HDIM) v = 0.f;                // pad cols -> 0
                    sO[(rl + r) * OSTRIDE + cl] = __float2bfloat16(v);
                }
            }
        }
        __syncthreads();
        __hip_bfloat16* Cp = (__hip_bfloat16*)C;
#pragma unroll
        for (int q = 0; q < 8; ++q) {
            const int flat = tid + q * 256;        // 0..2047
            const int rl = flat >> 4, c16 = flat & 15;
            const int gcol = n0 + c16 * 8;
            if (gcol < LDC)
                *(float4*)&Cp[(long)(m0 + rl) * LDC + gcol] =
                    *(const float4*)&sO[rl * OSTRIDE + c16 * 8];
        }
    } else {
        // fused h1 . W2 partial dot; W2=0 past HDIM kills padded-col relu(b1)
        float w2v[4];
#pragma unroll
        for (int j = 0; j < 4; ++j) {
            int col = n0 + waveN * 64 + j * 16 + l16;
            w2v[j] = (col < HDIM) ? W2[col] : 0.f;
        }
        const int slot = blockIdx.x * 2 + waveN;
#pragma unroll
        for (int i = 0; i < 4; ++i) {
#pragma unroll
            for (int r = 0; r < 4; ++r) {
                float p = 0.f;
#pragma unroll
                for (int j = 0; j < 4; ++j) {
                    float v = acc[i][j][r] + bias;
                    v = v > 0.f ? v : 0.f;
                    p += v * w2v[j];
                }
                p += __shfl_xor(p, 1); p += __shfl_xor(p, 2);
                p += __shfl_xor(p, 4); p += __shfl_xor(p, 8);
                if (l16 == 0) {
                    int row = m0 + waveM * 64 + i * 16 + quad * 4 + r;
                    ((float*)C)[(long)row * 8 + slot] = p;
                }
            }
        }
    }
}

// ---------------- k4: final combine + sigmoid ----------------
__global__ __launch_bounds__(256) void final_kernel(
    const float* __restrict__ partial, const float* __restrict__ b2p,
    const float* __restrict__ fs, float* __restrict__ out)
{
    const int s = blockIdx.x * 256 + threadIdx.x;
    const float4 p0 = *(const float4*)(partial + (long)s * 8);
    const float4 p1 = *(const float4*)(partial + (long)s * 8 + 4);
    float sum = (p0.x + p0.y) + (p0.z + p0.w) + (p1.x + p1.y) + (p1.z + p1.w);
    float h = sum + b2p[0];
    h = h > 0.f ? h : 0.f;
    float z = fs[s] + h;
    out[s] = 1.f / (1.f + __expf(-z));
}

extern "C" void kernel_launch(void* const* d_in, const int* in_sizes, int n_in,
                              void* d_out, int out_size, void* d_ws, size_t ws_size,
                              hipStream_t stream)
{
    // 0 index, 1 feats, 2 values, 3 bias, 4 weights, 5 embedding,
    // 6 W0, 7 b0, 8 W1, 9 b1, 10 W2, 11 b2, 12 batch_size
    const int*   feats     = (const int*)d_in[1];
    const float* values    = (const float*)d_in[2];
    const float* bias      = (const float*)d_in[3];
    const float* weights   = (const float*)d_in[4];
    const float* embedding = (const float*)d_in[5];
    const float* W0 = (const float*)d_in[6];
    const float* b0 = (const float*)d_in[7];
    const float* W1 = (const float*)d_in[8];
    const float* b1 = (const float*)d_in[9];
    const float* W2 = (const float*)d_in[10];
    const float* b2 = (const float*)d_in[11];

    char* ws = (char*)d_ws;
    size_t off = 0;
    auto alloc = [&](size_t bytes) {
        void* p = ws + off;
        off += (bytes + 255) & ~(size_t)255;
        return p;
    };
    float*          fs   = (float*)alloc((size_t)BATCH * 4);
    __hip_bfloat16* x    = (__hip_bfloat16*)alloc((size_t)BATCH * DDIM * 2);
    __hip_bfloat16* h0   = (__hip_bfloat16*)alloc((size_t)BATCH * HPAD * 2);
    float*          part = (float*)alloc((size_t)BATCH * 8 * 4);
    __hip_bfloat16* W0t  = (__hip_bfloat16*)alloc((size_t)NPAD * DDIM * 2);
    __hip_bfloat16* W1t  = (__hip_bfloat16*)alloc((size_t)NPAD * HPAD * 2);
    (void)ws_size; (void)in_sizes; (void)n_in; (void)out_size;

    prep_kernel<<<dim3(TBLK + GBLK), 256, 0, stream>>>(
        W0, W1, W0t, W1t, feats, values, bias, weights, embedding, fs, x);
    gemm_relu_kernel<DDIM, 0, HPAD>
        <<<dim3(NPAD / 128, BATCH / 128), 256, 0, stream>>>(
        x, W0t, b0, nullptr, (void*)h0);
    gemm_relu_kernel<HPAD, 1, 8>
        <<<dim3(NPAD / 128, BATCH / 128), 256, 0, stream>>>(
        h0, W1t, b1, W2, (void*)part);
    final_kernel<<<dim3(BATCH / 256), 256, 0, stream>>>(
        part, b2, fs, (float*)d_out);
}